// Round 8
// baseline (39644.498 us; speedup 1.0000x reference)
//
#include <hip/hip_runtime.h>
#include <cstdint>
#include <cstddef>

#define N_ 64
#define T_ 512
#define D_ 1024
#define H_ 1024
#define FH 4096  // 4*H

typedef __attribute__((ext_vector_type(8))) short bf16x8;
typedef __attribute__((ext_vector_type(4))) float f32x4;

static __device__ __forceinline__ uint16_t f2bf_(float f) {
  union { float f; uint32_t u; } v; v.f = f;
  uint32_t u = v.u + 0x7FFFu + ((v.u >> 16) & 1u);
  return (uint16_t)(u >> 16);
}
static __device__ __forceinline__ float bf2f_(uint16_t s) {
  union { uint32_t u; float f; } v; v.u = ((uint32_t)s) << 16;
  return v.f;
}

// ---------------------------------------------------------------------------
// Pack W [1024][4096] into MFMA B-fragment order, split bf16 hi/lo (proven).
// col c = lane&15 -> (gate g=c>>2, jj=c&3) of block bid; k = kc*32 +
// (lane>>4)*8 + e. dst unit = bid*2048 + kc*64 + lane. 2048 x 256 grid.
// ---------------------------------------------------------------------------
__global__ __launch_bounds__(256) void pack_w_k(const float* __restrict__ W,
                                                ushort* __restrict__ hi,
                                                ushort* __restrict__ lo) {
  const int i = blockIdx.x * 256 + threadIdx.x;  // 524288 = 256*32*64
  const int lane = i & 63, kc = (i >> 6) & 31, bid = i >> 11;
  const int c = lane & 15;
  const int col = (c >> 2) * H_ + (bid << 2) + (c & 3);
  const int k0 = (kc << 5) + ((lane >> 4) << 3);
  const size_t o = ((size_t)(bid * 32 + kc) * 64 + lane) * 8;
#pragma unroll
  for (int e = 0; e < 8; ++e) {
    float v = W[(size_t)(k0 + e) * FH + col];
    ushort h = f2bf_(v);
    hi[o + e] = h;
    lo[o + e] = f2bf_(v - bf2f_(h));
  }
}

// ---------------------------------------------------------------------------
// Elementwise f32 -> bf16 hi/lo split. One float4 per thread. Optionally
// zeroes the 9 grid-barrier counters (root + 8 leaves, 128-B spaced).
// ---------------------------------------------------------------------------
__global__ __launch_bounds__(256) void split_f32_k(const float* __restrict__ src,
                                                   ushort* __restrict__ hi,
                                                   ushort* __restrict__ lo,
                                                   unsigned* bar) {
  if (bar != nullptr && blockIdx.x == 0 && threadIdx.x < 9)
    bar[threadIdx.x * 32] = 0u;
  const size_t i = (size_t)blockIdx.x * 256 + threadIdx.x;
  float4 v = reinterpret_cast<const float4*>(src)[i];
  ushort4 h, l;
  h.x = f2bf_(v.x); l.x = f2bf_(v.x - bf2f_(h.x));
  h.y = f2bf_(v.y); l.y = f2bf_(v.y - bf2f_(h.y));
  h.z = f2bf_(v.z); l.z = f2bf_(v.z - bf2f_(h.z));
  h.w = f2bf_(v.w); l.w = f2bf_(v.w - bf2f_(h.w));
  reinterpret_cast<ushort4*>(hi)[i] = h;
  reinterpret_cast<ushort4*>(lo)[i] = l;
}

// ---------------------------------------------------------------------------
// Persistent fused LSTM scan, round-7 skeleton + latency fixes:
// - depth-2 double-buffered register prefetch of A and B fragments (4-kc
//   chunks, 32 loads in flight, macro-unrolled static indexing)
// - __launch_bounds__(512,2): up to 256 VGPR
// - two-level grid barrier: 8 leaf counters (bid&7, 128-B spaced) -> root
// 256 blocks x 512 thr; block owns 4 h-cols. Waves: mt=w&3 (16-row M tile),
// kh=w>>2: 0 -> h@Wh, 1 -> x_t@Wx. Split-bf16: D = Ah*Bh + Ah*Bl + Al*Bh.
// LDS 8.7 KB -> >=4 blocks/CU capacity, co-residency safe.
// ---------------------------------------------------------------------------
__global__ __launch_bounds__(512, 2) void lstm_persist_mfma(
    const ushort* __restrict__ Whh, const ushort* __restrict__ Whl,
    const ushort* __restrict__ Wxh, const ushort* __restrict__ Wxl,
    const ushort* __restrict__ xh, const ushort* __restrict__ xl,
    const float* __restrict__ bias,
    ushort* __restrict__ hb0h, ushort* __restrict__ hb0l,
    ushort* __restrict__ hb1h, ushort* __restrict__ hb1l,
    float* __restrict__ out, unsigned* __restrict__ bar) {
  __shared__ float pre[128 * 17];

  const int tid = threadIdx.x, bid = blockIdx.x;
  const int lane = tid & 63, w = tid >> 6;
  const int mt = w & 3, kh = w >> 2;
  const int arow = (mt << 4) | (lane & 15);
  const int kg = lane >> 4;
  const int dc = lane & 15, dr = (lane >> 4) << 2;
  const int en = tid >> 2, ejj = tid & 3;

  float bias4[4] = {0.f, 0.f, 0.f, 0.f};
  float creg = 0.f;
  if (tid < 256) {
#pragma unroll
    for (int g = 0; g < 4; ++g) bias4[g] = bias[g * H_ + (bid << 2) + ejj];
  }

  // B fragment bases (bf16x8 units); stride per kc = 64 units
  const bf16x8* Bh = reinterpret_cast<const bf16x8*>(kh ? Wxh : Whh) +
                     (size_t)bid * 2048 + lane;
  const bf16x8* Bl = reinterpret_cast<const bf16x8*>(kh ? Wxl : Whl) +
                     (size_t)bid * 2048 + lane;

  const ushort* rdh[2] = {hb0h, hb1h};
  const ushort* rdl[2] = {hb0l, hb1l};
  ushort* wrh[2] = {hb0h, hb1h};
  ushort* wrl[2] = {hb0l, hb1l};

  unsigned* const leaf = bar + 32 + ((bid & 7) << 5);

  for (int t = 0; t < T_; ++t) {
    const ushort *Ah, *Al;
    if (kh == 0) {
      Ah = rdh[t & 1] + arow * 1024 + (kg << 3);
      Al = rdl[t & 1] + arow * 1024 + (kg << 3);
    } else {
      const size_t ro = ((size_t)arow * T_ + t) * D_ + (kg << 3);
      Ah = xh + ro;
      Al = xl + ro;
    }

    f32x4 acc0 = {0.f, 0.f, 0.f, 0.f};
    f32x4 acc1 = {0.f, 0.f, 0.f, 0.f};

    bf16x8 pAH0, pAH1, pAH2, pAH3, pAL0, pAL1, pAL2, pAL3;
    bf16x8 pBH0, pBH1, pBH2, pBH3, pBL0, pBL1, pBL2, pBL3;
    bf16x8 qAH0, qAH1, qAH2, qAH3, qAL0, qAL1, qAL2, qAL3;
    bf16x8 qBH0, qBH1, qBH2, qBH3, qBL0, qBL1, qBL2, qBL3;

#define LOADC(P, CH)                                                          \
  {                                                                           \
    const int kb = (CH) << 2;                                                 \
    P##AH0 = *reinterpret_cast<const bf16x8*>(Ah + ((kb + 0) << 5));          \
    P##AH1 = *reinterpret_cast<const bf16x8*>(Ah + ((kb + 1) << 5));          \
    P##AH2 = *reinterpret_cast<const bf16x8*>(Ah + ((kb + 2) << 5));          \
    P##AH3 = *reinterpret_cast<const bf16x8*>(Ah + ((kb + 3) << 5));          \
    P##AL0 = *reinterpret_cast<const bf16x8*>(Al + ((kb + 0) << 5));          \
    P##AL1 = *reinterpret_cast<const bf16x8*>(Al + ((kb + 1) << 5));          \
    P##AL2 = *reinterpret_cast<const bf16x8*>(Al + ((kb + 2) << 5));          \
    P##AL3 = *reinterpret_cast<const bf16x8*>(Al + ((kb + 3) << 5));          \
    P##BH0 = Bh[(kb + 0) << 6];                                               \
    P##BH1 = Bh[(kb + 1) << 6];                                               \
    P##BH2 = Bh[(kb + 2) << 6];                                               \
    P##BH3 = Bh[(kb + 3) << 6];                                               \
    P##BL0 = Bl[(kb + 0) << 6];                                               \
    P##BL1 = Bl[(kb + 1) << 6];                                               \
    P##BL2 = Bl[(kb + 2) << 6];                                               \
    P##BL3 = Bl[(kb + 3) << 6];                                               \
  }

#define COMP(P)                                                               \
  {                                                                           \
    acc0 = __builtin_amdgcn_mfma_f32_16x16x32_bf16(P##AH0, P##BH0, acc0, 0, 0, 0); \
    acc1 = __builtin_amdgcn_mfma_f32_16x16x32_bf16(P##AH1, P##BH1, acc1, 0, 0, 0); \
    acc0 = __builtin_amdgcn_mfma_f32_16x16x32_bf16(P##AH0, P##BL0, acc0, 0, 0, 0); \
    acc1 = __builtin_amdgcn_mfma_f32_16x16x32_bf16(P##AH1, P##BL1, acc1, 0, 0, 0); \
    acc0 = __builtin_amdgcn_mfma_f32_16x16x32_bf16(P##AL0, P##BH0, acc0, 0, 0, 0); \
    acc1 = __builtin_amdgcn_mfma_f32_16x16x32_bf16(P##AL1, P##BH1, acc1, 0, 0, 0); \
    acc0 = __builtin_amdgcn_mfma_f32_16x16x32_bf16(P##AH2, P##BH2, acc0, 0, 0, 0); \
    acc1 = __builtin_amdgcn_mfma_f32_16x16x32_bf16(P##AH3, P##BH3, acc1, 0, 0, 0); \
    acc0 = __builtin_amdgcn_mfma_f32_16x16x32_bf16(P##AH2, P##BL2, acc0, 0, 0, 0); \
    acc1 = __builtin_amdgcn_mfma_f32_16x16x32_bf16(P##AH3, P##BL3, acc1, 0, 0, 0); \
    acc0 = __builtin_amdgcn_mfma_f32_16x16x32_bf16(P##AL2, P##BH2, acc0, 0, 0, 0); \
    acc1 = __builtin_amdgcn_mfma_f32_16x16x32_bf16(P##AL3, P##BH3, acc1, 0, 0, 0); \
  }

    LOADC(p, 0)
    LOADC(q, 1) COMP(p)
    LOADC(p, 2) COMP(q)
    LOADC(q, 3) COMP(p)
    LOADC(p, 4) COMP(q)
    LOADC(q, 5) COMP(p)
    LOADC(p, 6) COMP(q)
    LOADC(q, 7) COMP(p)
    COMP(q)
#undef LOADC
#undef COMP

    f32x4 accs = acc0 + acc1;

    // D layout (m89-verified): col = lane&15, row = (lane>>4)*4 + r
#pragma unroll
    for (int r = 0; r < 4; ++r)
      pre[((kh << 6) + (mt << 4) + dr + r) * 17 + dc] = accs[r];
    __syncthreads();

    if (tid < 256) {
      float a[4];
#pragma unroll
      for (int g = 0; g < 4; ++g)
        a[g] = pre[en * 17 + (g << 2) + ejj] +
               pre[(64 + en) * 17 + (g << 2) + ejj] + bias4[g];
      float iv = 1.f / (1.f + __expf(-a[0]));
      float fv = 1.f / (1.f + __expf(-a[1]));
      float ov = 1.f / (1.f + __expf(-a[2]));
      float gv = tanhf(a[3]);
      creg = fmaf(fv, creg, iv * gv);
      float hn = ov * tanhf(creg);
      out[(size_t)en * ((size_t)T_ * H_) + (size_t)t * H_ + (bid << 2) + ejj] = hn;
      const int o = (t + 1) & 1;
      const int hx = en * H_ + (bid << 2) + ejj;
      ushort hh = f2bf_(hn);
      wrh[o][hx] = hh;
      wrl[o][hx] = f2bf_(hn - bf2f_(hh));
    }

    // ---- two-level grid barrier (leaf: 32 blocks each -> root: 8) ----
    __threadfence();
    __syncthreads();
    if (tid == 0) {
      unsigned old = __hip_atomic_fetch_add(leaf, 1u, __ATOMIC_ACQ_REL,
                                            __HIP_MEMORY_SCOPE_AGENT);
      if (old == 32u * (unsigned)(t + 1) - 1u)
        __hip_atomic_fetch_add(bar, 1u, __ATOMIC_ACQ_REL,
                               __HIP_MEMORY_SCOPE_AGENT);
      const unsigned tgt = 8u * (unsigned)(t + 1);
      while (__hip_atomic_load(bar, __ATOMIC_ACQUIRE,
                               __HIP_MEMORY_SCOPE_AGENT) < tgt)
        __builtin_amdgcn_s_sleep(2);
    }
    __syncthreads();
  }
}

// ---------------------------------------------------------------------------
// Fallback (tiny ws): fused per-step VALU kernel (round-1 proven). Slow.
// ---------------------------------------------------------------------------
__global__ __launch_bounds__(256) void lstm_step_fb(
    const float* __restrict__ xt, const float* __restrict__ Wx,
    const float* __restrict__ Wh, const float* __restrict__ bias,
    const float* __restrict__ h_prev, long long hstride,
    float* __restrict__ cbuf, float* __restrict__ h_out, int first) {
  __shared__ float hS[32][128];
  __shared__ float wT[32][132];
  __shared__ float pre[32][34];
  const int tid = threadIdx.x;
  const int colblk = blockIdx.x & 127;
  const int nh = blockIdx.x >> 7;
  const int j0 = colblk << 3;
  const int n0 = nh << 5;
  const int ng = tid >> 4, cg2 = tid & 15;
  const int na = ng << 1, ca = cg2 << 1;

  float acc[2][2] = {{0.f, 0.f}, {0.f, 0.f}};

#pragma unroll
  for (int pr = 0; pr < 2; ++pr) {
    const float* src = (pr == 0) ? h_prev : xt;
    long long sstr = (pr == 0) ? hstride : (long long)T_ * D_;
    const float* W = (pr == 0) ? Wh : Wx;
    for (int k0 = 0; k0 < 1024; k0 += 128) {
      __syncthreads();
#pragma unroll
      for (int p = 0; p < 4; ++p) {
        int idx = tid + (p << 8);
        int r = idx >> 5, c4 = (idx & 31) << 2;
        *reinterpret_cast<float4*>(&hS[r][c4]) =
            *reinterpret_cast<const float4*>(src + (size_t)(n0 + r) * sstr + k0 + c4);
      }
#pragma unroll
      for (int p = 0; p < 4; ++p) {
        int idx = tid + (p << 8);
        int k = idx >> 3, sub = idx & 7;
        int g = sub >> 1, hf = (sub & 1) << 2;
        float4 v = *reinterpret_cast<const float4*>(
            W + (size_t)(k0 + k) * FH + g * H_ + j0 + hf);
        int cb = (g << 3) + hf;
        wT[cb][k] = v.x; wT[cb + 1][k] = v.y; wT[cb + 2][k] = v.z; wT[cb + 3][k] = v.w;
      }
      __syncthreads();
#pragma unroll
      for (int kk = 0; kk < 128; kk += 4) {
        float4 h0v = *reinterpret_cast<const float4*>(&hS[na][kk]);
        float4 h1v = *reinterpret_cast<const float4*>(&hS[na + 1][kk]);
        float4 w0 = *reinterpret_cast<const float4*>(&wT[ca][kk]);
        float4 w1 = *reinterpret_cast<const float4*>(&wT[ca + 1][kk]);
        acc[0][0] = fmaf(h0v.x, w0.x, acc[0][0]); acc[0][0] = fmaf(h0v.y, w0.y, acc[0][0]);
        acc[0][0] = fmaf(h0v.z, w0.z, acc[0][0]); acc[0][0] = fmaf(h0v.w, w0.w, acc[0][0]);
        acc[0][1] = fmaf(h0v.x, w1.x, acc[0][1]); acc[0][1] = fmaf(h0v.y, w1.y, acc[0][1]);
        acc[0][1] = fmaf(h0v.z, w1.z, acc[0][1]); acc[0][1] = fmaf(h0v.w, w1.w, acc[0][1]);
        acc[1][0] = fmaf(h1v.x, w0.x, acc[1][0]); acc[1][0] = fmaf(h1v.y, w0.y, acc[1][0]);
        acc[1][0] = fmaf(h1v.z, w0.z, acc[1][0]); acc[1][0] = fmaf(h1v.w, w0.w, acc[1][0]);
        acc[1][1] = fmaf(h1v.x, w1.x, acc[1][1]); acc[1][1] = fmaf(h1v.y, w1.y, acc[1][1]);
        acc[1][1] = fmaf(h1v.z, w1.z, acc[1][1]); acc[1][1] = fmaf(h1v.w, w1.w, acc[1][1]);
      }
    }
  }

  pre[na][ca] = acc[0][0];
  pre[na][ca + 1] = acc[0][1];
  pre[na + 1][ca] = acc[1][0];
  pre[na + 1][ca + 1] = acc[1][1];
  __syncthreads();

  const int nl = tid >> 3, jl = tid & 7;
  const int n = n0 + nl;
  const int jg = j0 + jl;
  float ai = pre[nl][jl] + bias[jg];
  float af = pre[nl][8 + jl] + bias[H_ + jg];
  float ao = pre[nl][16 + jl] + bias[2 * H_ + jg];
  float ag = pre[nl][24 + jl] + bias[3 * H_ + jg];
  float cp = first ? 0.0f : cbuf[n * H_ + jg];
  float iv = 1.f / (1.f + __expf(-ai));
  float fv = 1.f / (1.f + __expf(-af));
  float ov = 1.f / (1.f + __expf(-ao));
  float gv = tanhf(ag);
  float cn = fmaf(fv, cp, iv * gv);
  cbuf[n * H_ + jg] = cn;
  h_out[(size_t)n * ((size_t)T_ * H_) + jg] = ov * tanhf(cn);
}

// ---------------------------------------------------------------------------
extern "C" void kernel_launch(void* const* d_in, const int* in_sizes, int n_in,
                              void* d_out, int out_size, void* d_ws, size_t ws_size,
                              hipStream_t stream) {
  (void)in_sizes; (void)n_in; (void)out_size;
  const float* x  = (const float*)d_in[0];
  const float* h0 = (const float*)d_in[1];
  const float* Wx = (const float*)d_in[2];
  const float* Wh = (const float*)d_in[3];
  const float* b  = (const float*)d_in[4];
  float* out = (float*)d_out;

  const size_t MB = 1u << 20;
  char* p = (char*)d_ws;

  if (ws_size >= 163 * MB) {
    unsigned* bar = (unsigned*)p;
    ushort* Whh = (ushort*)(p + 1 * MB);
    ushort* Whl = (ushort*)(p + 9 * MB);
    ushort* Wxh = (ushort*)(p + 17 * MB);
    ushort* Wxl = (ushort*)(p + 25 * MB);
    ushort* hb0h = (ushort*)(p + 33 * MB);
    ushort* hb0l = hb0h + 65536;
    ushort* hb1h = hb0l + 65536;
    ushort* hb1l = hb1h + 65536;
    ushort* xh = (ushort*)(p + 34 * MB);   // 64 MB
    ushort* xl = (ushort*)(p + 98 * MB);   // 64 MB

    pack_w_k<<<dim3(2048), dim3(256), 0, stream>>>(Wh, Whh, Whl);
    pack_w_k<<<dim3(2048), dim3(256), 0, stream>>>(Wx, Wxh, Wxl);
    // x: 64*512*1024 floats = 8,388,608 float4 -> 32768 blocks (zeroes bar)
    split_f32_k<<<dim3(32768), dim3(256), 0, stream>>>(x, xh, xl, bar);
    // h0: 64*1024 floats = 16384 float4 -> 64 blocks
    split_f32_k<<<dim3(64), dim3(256), 0, stream>>>(h0, hb0h, hb0l, nullptr);

    lstm_persist_mfma<<<dim3(256), dim3(512), 0, stream>>>(
        Whh, Whl, Wxh, Wxl, xh, xl, b, hb0h, hb0l, hb1h, hb1l, out, bar);
  } else {
    float* cbuf = (float*)p;  // 256 KB
    for (int t = 0; t < T_; ++t) {
      const float* hp = (t == 0) ? h0 : out + (size_t)(t - 1) * H_;
      long long hstr = (t == 0) ? (long long)H_ : (long long)T_ * H_;
      lstm_step_fb<<<dim3(256), dim3(256), 0, stream>>>(
          x + (size_t)t * D_, Wx, Wh, b, hp, hstr, cbuf,
          out + (size_t)t * H_, t == 0);
    }
  }
}

// Round 9
// 13680.389 us; speedup vs baseline: 2.8979x; 2.8979x over previous
//
#include <hip/hip_runtime.h>
#include <cstdint>
#include <cstddef>

#define N_ 64
#define T_ 512
#define D_ 1024
#define H_ 1024
#define FH 4096  // 4*H

typedef __attribute__((ext_vector_type(8))) short bf16x8;
typedef __attribute__((ext_vector_type(4))) float f32x4;

static __device__ __forceinline__ uint16_t f2bf_(float f) {
  union { float f; uint32_t u; } v; v.f = f;
  uint32_t u = v.u + 0x7FFFu + ((v.u >> 16) & 1u);
  return (uint16_t)(u >> 16);
}
static __device__ __forceinline__ float bf2f_(uint16_t s) {
  union { uint32_t u; float f; } v; v.u = ((uint32_t)s) << 16;
  return v.f;
}
// split u64 of two packed (hi:lo) elements into hi-pair / lo-pair u32s
static __device__ __forceinline__ void unpk2_(unsigned long long e,
                                              uint32_t& hi, uint32_t& lo) {
  uint32_t a = (uint32_t)e, b = (uint32_t)(e >> 32);
  hi = (a >> 16) | (b & 0xFFFF0000u);
  lo = (a & 0xFFFFu) | (b << 16);
}

#define ALD(p) __hip_atomic_load((unsigned long long*)(p), __ATOMIC_RELAXED, \
                                 __HIP_MEMORY_SCOPE_AGENT)

// ---------------------------------------------------------------------------
// Pack W [1024][4096] into MFMA B-fragment order, split bf16 hi/lo (proven).
// ---------------------------------------------------------------------------
__global__ __launch_bounds__(256) void pack_w_k(const float* __restrict__ W,
                                                ushort* __restrict__ hi,
                                                ushort* __restrict__ lo) {
  const int i = blockIdx.x * 256 + threadIdx.x;  // 524288 = 256*32*64
  const int lane = i & 63, kc = (i >> 6) & 31, bid = i >> 11;
  const int c = lane & 15;
  const int col = (c >> 2) * H_ + (bid << 2) + (c & 3);
  const int k0 = (kc << 5) + ((lane >> 4) << 3);
  const size_t o = ((size_t)(bid * 32 + kc) * 64 + lane) * 8;
#pragma unroll
  for (int e = 0; e < 8; ++e) {
    float v = W[(size_t)(k0 + e) * FH + col];
    ushort h = f2bf_(v);
    hi[o + e] = h;
    lo[o + e] = f2bf_(v - bf2f_(h));
  }
}

// ---------------------------------------------------------------------------
// x: f32 -> bf16 hi/lo planes. Zeroes the 9 barrier counters in block 0.
// ---------------------------------------------------------------------------
__global__ __launch_bounds__(256) void split_f32_k(const float* __restrict__ src,
                                                   ushort* __restrict__ hi,
                                                   ushort* __restrict__ lo,
                                                   unsigned* bar) {
  if (bar != nullptr && blockIdx.x == 0 && threadIdx.x < 9)
    bar[threadIdx.x * 32] = 0u;
  const size_t i = (size_t)blockIdx.x * 256 + threadIdx.x;
  float4 v = reinterpret_cast<const float4*>(src)[i];
  ushort4 h, l;
  h.x = f2bf_(v.x); l.x = f2bf_(v.x - bf2f_(h.x));
  h.y = f2bf_(v.y); l.y = f2bf_(v.y - bf2f_(h.y));
  h.z = f2bf_(v.z); l.z = f2bf_(v.z - bf2f_(h.z));
  h.w = f2bf_(v.w); l.w = f2bf_(v.w - bf2f_(h.w));
  reinterpret_cast<ushort4*>(hi)[i] = h;
  reinterpret_cast<ushort4*>(lo)[i] = l;
}

// h0 f32 -> packed u32 (hi16:lo16). 64 blocks x 256 thr x 4 elems.
__global__ __launch_bounds__(256) void conv_h0pk_k(const float* __restrict__ src,
                                                   uint32_t* __restrict__ dst) {
  const int i = blockIdx.x * 256 + threadIdx.x;  // 16384 float4s
  float4 v = reinterpret_cast<const float4*>(src)[i];
  uint4 o;
  {
    ushort h = f2bf_(v.x); o.x = ((uint32_t)h << 16) | f2bf_(v.x - bf2f_(h));
  }
  {
    ushort h = f2bf_(v.y); o.y = ((uint32_t)h << 16) | f2bf_(v.y - bf2f_(h));
  }
  {
    ushort h = f2bf_(v.z); o.z = ((uint32_t)h << 16) | f2bf_(v.z - bf2f_(h));
  }
  {
    ushort h = f2bf_(v.w); o.w = ((uint32_t)h << 16) | f2bf_(v.w - bf2f_(h));
  }
  reinterpret_cast<uint4*>(dst)[i] = o;
}

// ---------------------------------------------------------------------------
// Persistent fused LSTM scan, FENCE-FREE steps:
// - h ping-pong: packed u32, written w/ relaxed-agent atomic stores
//   (write-through), read w/ relaxed-agent u64 atomic loads (bypass L1/L2).
// - barrier: all-RELAXED two-level counter; manual vmcnt drain; no
//   __threadfence, no acquire-invalidate (the round-7/8 ~75us/step killer).
// - Wh resident in LDS (64 KB, staged once); Wx global-cacheable (L2-hot now
//   that nothing invalidates it); x planes cacheable (read-only).
// 256 blocks x 512 thr; block owns 4 h-cols. Waves: mt=w&3, kh=w>>2
// (0 -> h@Wh, 1 -> x_t@Wx). Split-bf16: D = Ah*Bh + Ah*Bl + Al*Bh.
// LDS 74240 B -> 2 blocks/CU capacity (same co-residency safety as r7/r8).
// ---------------------------------------------------------------------------
__global__ __launch_bounds__(512, 2) void lstm_persist_mfma(
    const ushort* __restrict__ Whh_g, const ushort* __restrict__ Whl_g,
    const ushort* __restrict__ Wxh, const ushort* __restrict__ Wxl,
    const ushort* __restrict__ xh, const ushort* __restrict__ xl,
    const float* __restrict__ bias,
    uint32_t* __restrict__ hpk0, uint32_t* __restrict__ hpk1,
    float* __restrict__ out, unsigned* __restrict__ bar) {
  extern __shared__ char ldsraw[];
  bf16x8* const WhH = (bf16x8*)ldsraw;       // 2048 units (32 KB)
  bf16x8* const WhL = WhH + 2048;            // 2048 units (32 KB)
  float* const pre = (float*)(WhL + 2048);   // 128*17 floats (8704 B)

  const int tid = threadIdx.x, bid = blockIdx.x;
  const int lane = tid & 63, w = tid >> 6;
  const int mt = w & 3, kh = w >> 2;
  const int arow = (mt << 4) | (lane & 15);
  const int kg = lane >> 4;
  const int dc = lane & 15, dr = (lane >> 4) << 2;
  const int en = tid >> 2, ejj = tid & 3;

  float bias4[4] = {0.f, 0.f, 0.f, 0.f};
  float creg = 0.f;
  if (tid < 256) {
#pragma unroll
    for (int g = 0; g < 4; ++g) bias4[g] = bias[g * H_ + (bid << 2) + ejj];
  }

  // one-time Wh stage into LDS (identity copy of packed layout)
  {
    const bf16x8* gh = reinterpret_cast<const bf16x8*>(Whh_g) + (size_t)bid * 2048;
    const bf16x8* gl = reinterpret_cast<const bf16x8*>(Whl_g) + (size_t)bid * 2048;
#pragma unroll
    for (int r = 0; r < 4; ++r) {
      int u = tid + (r << 9);
      WhH[u] = gh[u];
      WhL[u] = gl[u];
    }
  }
  __syncthreads();

  // Wx global fragment bases (x-wave)
  const bf16x8* Bxh = reinterpret_cast<const bf16x8*>(Wxh) + (size_t)bid * 2048 + lane;
  const bf16x8* Bxl = reinterpret_cast<const bf16x8*>(Wxl) + (size_t)bid * 2048 + lane;

  uint32_t* hpk[2] = {hpk0, hpk1};
  unsigned* const leaf = bar + 32 + ((bid & 7) << 5);

  for (int t = 0; t < T_; ++t) {
    f32x4 acc0 = {0.f, 0.f, 0.f, 0.f};
    f32x4 acc1 = {0.f, 0.f, 0.f, 0.f};

    if (kh == 0) {
      // ---- h @ Wh : A via bypassing u64 atomic loads, B from LDS ----
      const unsigned long long* Apk =
          (const unsigned long long*)hpk[t & 1] + arow * 512 + kg * 4;

      unsigned long long pa0, pa1, pa2, pa3, pb0, pb1, pb2, pb3;
      unsigned long long pc0, pc1, pc2, pc3, pd0, pd1, pd2, pd3;
      unsigned long long qa0, qa1, qa2, qa3, qb0, qb1, qb2, qb3;
      unsigned long long qc0, qc1, qc2, qc3, qd0, qd1, qd2, qd3;

#define HLD(P, CH)                                                            \
  {                                                                           \
    const unsigned long long* ap_ = Apk + ((CH) << 6);                        \
    P##a0 = ALD(ap_ + 0);  P##a1 = ALD(ap_ + 1);                              \
    P##a2 = ALD(ap_ + 2);  P##a3 = ALD(ap_ + 3);                              \
    P##b0 = ALD(ap_ + 16); P##b1 = ALD(ap_ + 17);                             \
    P##b2 = ALD(ap_ + 18); P##b3 = ALD(ap_ + 19);                             \
    P##c0 = ALD(ap_ + 32); P##c1 = ALD(ap_ + 33);                             \
    P##c2 = ALD(ap_ + 34); P##c3 = ALD(ap_ + 35);                             \
    P##d0 = ALD(ap_ + 48); P##d1 = ALD(ap_ + 49);                             \
    P##d2 = ALD(ap_ + 50); P##d3 = ALD(ap_ + 51);                             \
  }

#define HKC(E0, E1, E2, E3, KCG, ACC)                                         \
  {                                                                           \
    union { uint32_t u[4]; bf16x8 v; } fh_, fl_;                              \
    unpk2_(E0, fh_.u[0], fl_.u[0]);                                           \
    unpk2_(E1, fh_.u[1], fl_.u[1]);                                           \
    unpk2_(E2, fh_.u[2], fl_.u[2]);                                           \
    unpk2_(E3, fh_.u[3], fl_.u[3]);                                           \
    bf16x8 bh_ = WhH[((KCG) << 6) + lane];                                    \
    bf16x8 bl_ = WhL[((KCG) << 6) + lane];                                    \
    ACC = __builtin_amdgcn_mfma_f32_16x16x32_bf16(fh_.v, bh_, ACC, 0, 0, 0);  \
    ACC = __builtin_amdgcn_mfma_f32_16x16x32_bf16(fh_.v, bl_, ACC, 0, 0, 0);  \
    ACC = __builtin_amdgcn_mfma_f32_16x16x32_bf16(fl_.v, bh_, ACC, 0, 0, 0);  \
  }

#define HCOMP(P, CH)                                                          \
  HKC(P##a0, P##a1, P##a2, P##a3, (CH) * 4 + 0, acc0)                         \
  HKC(P##b0, P##b1, P##b2, P##b3, (CH) * 4 + 1, acc1)                         \
  HKC(P##c0, P##c1, P##c2, P##c3, (CH) * 4 + 2, acc0)                         \
  HKC(P##d0, P##d1, P##d2, P##d3, (CH) * 4 + 3, acc1)

      HLD(p, 0)
      HLD(q, 1) HCOMP(p, 0)
      HLD(p, 2) HCOMP(q, 1)
      HLD(q, 3) HCOMP(p, 2)
      HLD(p, 4) HCOMP(q, 3)
      HLD(q, 5) HCOMP(p, 4)
      HLD(p, 6) HCOMP(q, 5)
      HLD(q, 7) HCOMP(p, 6)
      HCOMP(q, 7)
#undef HLD
#undef HKC
#undef HCOMP
    } else {
      // ---- x_t @ Wx : cacheable loads (round-8 structure, proven) ----
      const ushort* Ah = xh + ((size_t)arow * T_ + t) * D_ + (kg << 3);
      const ushort* Al = xl + ((size_t)arow * T_ + t) * D_ + (kg << 3);

      bf16x8 pAH0, pAH1, pAH2, pAH3, pAL0, pAL1, pAL2, pAL3;
      bf16x8 pBH0, pBH1, pBH2, pBH3, pBL0, pBL1, pBL2, pBL3;
      bf16x8 qAH0, qAH1, qAH2, qAH3, qAL0, qAL1, qAL2, qAL3;
      bf16x8 qBH0, qBH1, qBH2, qBH3, qBL0, qBL1, qBL2, qBL3;

#define XLD(P, CH)                                                            \
  {                                                                           \
    const int kb = (CH) << 2;                                                 \
    P##AH0 = *reinterpret_cast<const bf16x8*>(Ah + ((kb + 0) << 5));          \
    P##AH1 = *reinterpret_cast<const bf16x8*>(Ah + ((kb + 1) << 5));          \
    P##AH2 = *reinterpret_cast<const bf16x8*>(Ah + ((kb + 2) << 5));          \
    P##AH3 = *reinterpret_cast<const bf16x8*>(Ah + ((kb + 3) << 5));          \
    P##AL0 = *reinterpret_cast<const bf16x8*>(Al + ((kb + 0) << 5));          \
    P##AL1 = *reinterpret_cast<const bf16x8*>(Al + ((kb + 1) << 5));          \
    P##AL2 = *reinterpret_cast<const bf16x8*>(Al + ((kb + 2) << 5));          \
    P##AL3 = *reinterpret_cast<const bf16x8*>(Al + ((kb + 3) << 5));          \
    P##BH0 = Bxh[(kb + 0) << 6];                                              \
    P##BH1 = Bxh[(kb + 1) << 6];                                              \
    P##BH2 = Bxh[(kb + 2) << 6];                                              \
    P##BH3 = Bxh[(kb + 3) << 6];                                              \
    P##BL0 = Bxl[(kb + 0) << 6];                                              \
    P##BL1 = Bxl[(kb + 1) << 6];                                              \
    P##BL2 = Bxl[(kb + 2) << 6];                                              \
    P##BL3 = Bxl[(kb + 3) << 6];                                              \
  }

#define XCOMP(P)                                                              \
  {                                                                           \
    acc0 = __builtin_amdgcn_mfma_f32_16x16x32_bf16(P##AH0, P##BH0, acc0, 0, 0, 0); \
    acc1 = __builtin_amdgcn_mfma_f32_16x16x32_bf16(P##AH1, P##BH1, acc1, 0, 0, 0); \
    acc0 = __builtin_amdgcn_mfma_f32_16x16x32_bf16(P##AH0, P##BL0, acc0, 0, 0, 0); \
    acc1 = __builtin_amdgcn_mfma_f32_16x16x32_bf16(P##AH1, P##BL1, acc1, 0, 0, 0); \
    acc0 = __builtin_amdgcn_mfma_f32_16x16x32_bf16(P##AL0, P##BH0, acc0, 0, 0, 0); \
    acc1 = __builtin_amdgcn_mfma_f32_16x16x32_bf16(P##AL1, P##BH1, acc1, 0, 0, 0); \
    acc0 = __builtin_amdgcn_mfma_f32_16x16x32_bf16(P##AH2, P##BH2, acc0, 0, 0, 0); \
    acc1 = __builtin_amdgcn_mfma_f32_16x16x32_bf16(P##AH3, P##BH3, acc1, 0, 0, 0); \
    acc0 = __builtin_amdgcn_mfma_f32_16x16x32_bf16(P##AH2, P##BL2, acc0, 0, 0, 0); \
    acc1 = __builtin_amdgcn_mfma_f32_16x16x32_bf16(P##AH3, P##BL3, acc1, 0, 0, 0); \
    acc0 = __builtin_amdgcn_mfma_f32_16x16x32_bf16(P##AL2, P##BH2, acc0, 0, 0, 0); \
    acc1 = __builtin_amdgcn_mfma_f32_16x16x32_bf16(P##AL3, P##BH3, acc1, 0, 0, 0); \
  }

      XLD(p, 0)
      XLD(q, 1) XCOMP(p)
      XLD(p, 2) XCOMP(q)
      XLD(q, 3) XCOMP(p)
      XLD(p, 4) XCOMP(q)
      XLD(q, 5) XCOMP(p)
      XLD(p, 6) XCOMP(q)
      XLD(q, 7) XCOMP(p)
      XCOMP(q)
#undef XLD
#undef XCOMP
    }

    f32x4 accs = acc0 + acc1;

    // D layout (m89-verified): col = lane&15, row = (lane>>4)*4 + r
#pragma unroll
    for (int r = 0; r < 4; ++r)
      pre[((kh << 6) + (mt << 4) + dr + r) * 17 + dc] = accs[r];
    __syncthreads();

    if (tid < 256) {
      float a[4];
#pragma unroll
      for (int g = 0; g < 4; ++g)
        a[g] = pre[en * 17 + (g << 2) + ejj] +
               pre[(64 + en) * 17 + (g << 2) + ejj] + bias4[g];
      float iv = 1.f / (1.f + __expf(-a[0]));
      float fv = 1.f / (1.f + __expf(-a[1]));
      float ov = 1.f / (1.f + __expf(-a[2]));
      float gv = tanhf(a[3]);
      creg = fmaf(fv, creg, iv * gv);
      float hn = ov * tanhf(creg);
      out[(size_t)en * ((size_t)T_ * H_) + (size_t)t * H_ + (bid << 2) + ejj] = hn;
      ushort hh = f2bf_(hn);
      uint32_t pk = ((uint32_t)hh << 16) | f2bf_(hn - bf2f_(hh));
      __hip_atomic_store(&hpk[(t + 1) & 1][en * H_ + (bid << 2) + ejj], pk,
                         __ATOMIC_RELAXED, __HIP_MEMORY_SCOPE_AGENT);
    }

    // ---- fence-free two-level grid barrier (all relaxed atomics) ----
    asm volatile("s_waitcnt vmcnt(0)" ::: "memory");
    __syncthreads();
    if (tid == 0) {
      unsigned old = __hip_atomic_fetch_add(leaf, 1u, __ATOMIC_RELAXED,
                                            __HIP_MEMORY_SCOPE_AGENT);
      if (old == 32u * (unsigned)(t + 1) - 1u)
        __hip_atomic_fetch_add(bar, 1u, __ATOMIC_RELAXED,
                               __HIP_MEMORY_SCOPE_AGENT);
      while (__hip_atomic_load(bar, __ATOMIC_RELAXED,
                               __HIP_MEMORY_SCOPE_AGENT) < 8u * (unsigned)(t + 1))
        __builtin_amdgcn_s_sleep(1);
    }
    __syncthreads();
  }
}

// ---------------------------------------------------------------------------
// Fallback (tiny ws): fused per-step VALU kernel (round-1 proven). Slow.
// ---------------------------------------------------------------------------
__global__ __launch_bounds__(256) void lstm_step_fb(
    const float* __restrict__ xt, const float* __restrict__ Wx,
    const float* __restrict__ Wh, const float* __restrict__ bias,
    const float* __restrict__ h_prev, long long hstride,
    float* __restrict__ cbuf, float* __restrict__ h_out, int first) {
  __shared__ float hS[32][128];
  __shared__ float wT[32][132];
  __shared__ float pre[32][34];
  const int tid = threadIdx.x;
  const int colblk = blockIdx.x & 127;
  const int nh = blockIdx.x >> 7;
  const int j0 = colblk << 3;
  const int n0 = nh << 5;
  const int ng = tid >> 4, cg2 = tid & 15;
  const int na = ng << 1, ca = cg2 << 1;

  float acc[2][2] = {{0.f, 0.f}, {0.f, 0.f}};

#pragma unroll
  for (int pr = 0; pr < 2; ++pr) {
    const float* src = (pr == 0) ? h_prev : xt;
    long long sstr = (pr == 0) ? hstride : (long long)T_ * D_;
    const float* W = (pr == 0) ? Wh : Wx;
    for (int k0 = 0; k0 < 1024; k0 += 128) {
      __syncthreads();
#pragma unroll
      for (int p = 0; p < 4; ++p) {
        int idx = tid + (p << 8);
        int r = idx >> 5, c4 = (idx & 31) << 2;
        *reinterpret_cast<float4*>(&hS[r][c4]) =
            *reinterpret_cast<const float4*>(src + (size_t)(n0 + r) * sstr + k0 + c4);
      }
#pragma unroll
      for (int p = 0; p < 4; ++p) {
        int idx = tid + (p << 8);
        int k = idx >> 3, sub = idx & 7;
        int g = sub >> 1, hf = (sub & 1) << 2;
        float4 v = *reinterpret_cast<const float4*>(
            W + (size_t)(k0 + k) * FH + g * H_ + j0 + hf);
        int cb = (g << 3) + hf;
        wT[cb][k] = v.x; wT[cb + 1][k] = v.y; wT[cb + 2][k] = v.z; wT[cb + 3][k] = v.w;
      }
      __syncthreads();
#pragma unroll
      for (int kk = 0; kk < 128; kk += 4) {
        float4 h0v = *reinterpret_cast<const float4*>(&hS[na][kk]);
        float4 h1v = *reinterpret_cast<const float4*>(&hS[na + 1][kk]);
        float4 w0 = *reinterpret_cast<const float4*>(&wT[ca][kk]);
        float4 w1 = *reinterpret_cast<const float4*>(&wT[ca + 1][kk]);
        acc[0][0] = fmaf(h0v.x, w0.x, acc[0][0]); acc[0][0] = fmaf(h0v.y, w0.y, acc[0][0]);
        acc[0][0] = fmaf(h0v.z, w0.z, acc[0][0]); acc[0][0] = fmaf(h0v.w, w0.w, acc[0][0]);
        acc[0][1] = fmaf(h0v.x, w1.x, acc[0][1]); acc[0][1] = fmaf(h0v.y, w1.y, acc[0][1]);
        acc[0][1] = fmaf(h0v.z, w1.z, acc[0][1]); acc[0][1] = fmaf(h0v.w, w1.w, acc[0][1]);
        acc[1][0] = fmaf(h1v.x, w0.x, acc[1][0]); acc[1][0] = fmaf(h1v.y, w0.y, acc[1][0]);
        acc[1][0] = fmaf(h1v.z, w0.z, acc[1][0]); acc[1][0] = fmaf(h1v.w, w0.w, acc[1][0]);
        acc[1][1] = fmaf(h1v.x, w1.x, acc[1][1]); acc[1][1] = fmaf(h1v.y, w1.y, acc[1][1]);
        acc[1][1] = fmaf(h1v.z, w1.z, acc[1][1]); acc[1][1] = fmaf(h1v.w, w1.w, acc[1][1]);
      }
    }
  }

  pre[na][ca] = acc[0][0];
  pre[na][ca + 1] = acc[0][1];
  pre[na + 1][ca] = acc[1][0];
  pre[na + 1][ca + 1] = acc[1][1];
  __syncthreads();

  const int nl = tid >> 3, jl = tid & 7;
  const int n = n0 + nl;
  const int jg = j0 + jl;
  float ai = pre[nl][jl] + bias[jg];
  float af = pre[nl][8 + jl] + bias[H_ + jg];
  float ao = pre[nl][16 + jl] + bias[2 * H_ + jg];
  float ag = pre[nl][24 + jl] + bias[3 * H_ + jg];
  float cp = first ? 0.0f : cbuf[n * H_ + jg];
  float iv = 1.f / (1.f + __expf(-ai));
  float fv = 1.f / (1.f + __expf(-af));
  float ov = 1.f / (1.f + __expf(-ao));
  float gv = tanhf(ag);
  float cn = fmaf(fv, cp, iv * gv);
  cbuf[n * H_ + jg] = cn;
  h_out[(size_t)n * ((size_t)T_ * H_) + jg] = ov * tanhf(cn);
}

// ---------------------------------------------------------------------------
extern "C" void kernel_launch(void* const* d_in, const int* in_sizes, int n_in,
                              void* d_out, int out_size, void* d_ws, size_t ws_size,
                              hipStream_t stream) {
  (void)in_sizes; (void)n_in; (void)out_size;
  const float* x  = (const float*)d_in[0];
  const float* h0 = (const float*)d_in[1];
  const float* Wx = (const float*)d_in[2];
  const float* Wh = (const float*)d_in[3];
  const float* b  = (const float*)d_in[4];
  float* out = (float*)d_out;

  const size_t MB = 1u << 20;
  char* p = (char*)d_ws;

  if (ws_size >= 163 * MB) {
    unsigned* bar = (unsigned*)p;
    ushort* Whh = (ushort*)(p + 1 * MB);
    ushort* Whl = (ushort*)(p + 9 * MB);
    ushort* Wxh = (ushort*)(p + 17 * MB);
    ushort* Wxl = (ushort*)(p + 25 * MB);
    uint32_t* hpk0 = (uint32_t*)(p + 33 * MB);           // 256 KB
    uint32_t* hpk1 = (uint32_t*)(p + 33 * MB + 262144);  // 256 KB
    ushort* xh = (ushort*)(p + 34 * MB);   // 64 MB
    ushort* xl = (ushort*)(p + 98 * MB);   // 64 MB

    pack_w_k<<<dim3(2048), dim3(256), 0, stream>>>(Wh, Whh, Whl);
    pack_w_k<<<dim3(2048), dim3(256), 0, stream>>>(Wx, Wxh, Wxl);
    // x: 8,388,608 float4 -> 32768 blocks (zeroes bar counters)
    split_f32_k<<<dim3(32768), dim3(256), 0, stream>>>(x, xh, xl, bar);
    // h0 -> packed u32
    conv_h0pk_k<<<dim3(64), dim3(256), 0, stream>>>(h0, hpk0);

    const unsigned SH = 2048 * 16 * 2 + 128 * 17 * 4;  // 74240 B
    hipFuncSetAttribute((const void*)lstm_persist_mfma,
                        hipFuncAttributeMaxDynamicSharedMemorySize, (int)SH);
    lstm_persist_mfma<<<dim3(256), dim3(512), SH, stream>>>(
        Whh, Whl, Wxh, Wxl, xh, xl, b, hpk0, hpk1, out, bar);
  } else {
    float* cbuf = (float*)p;  // 256 KB
    for (int t = 0; t < T_; ++t) {
      const float* hp = (t == 0) ? h0 : out + (size_t)(t - 1) * H_;
      long long hstr = (t == 0) ? (long long)H_ : (long long)T_ * H_;
      lstm_step_fb<<<dim3(256), dim3(256), 0, stream>>>(
          x + (size_t)t * D_, Wx, Wh, b, hp, hstr, cbuf,
          out + (size_t)t * H_, t == 0);
    }
  }
}

// Round 10
// 10228.736 us; speedup vs baseline: 3.8758x; 1.3374x over previous
//
#include <hip/hip_runtime.h>
#include <cstdint>
#include <cstddef>

#define N_ 64
#define T_ 512
#define D_ 1024
#define H_ 1024
#define FH 4096  // 4*H

typedef __attribute__((ext_vector_type(8))) short bf16x8;
typedef __attribute__((ext_vector_type(4))) float f32x4;

static __device__ __forceinline__ uint16_t f2bf_(float f) {
  union { float f; uint32_t u; } v; v.f = f;
  uint32_t u = v.u + 0x7FFFu + ((v.u >> 16) & 1u);
  return (uint16_t)(u >> 16);
}
static __device__ __forceinline__ float bf2f_(uint16_t s) {
  union { uint32_t u; float f; } v; v.u = ((uint32_t)s) << 16;
  return v.f;
}
// split u64 of two packed (hi:lo) elements into hi-pair / lo-pair u32s
static __device__ __forceinline__ void unpk2_(unsigned long long e,
                                              uint32_t& hi, uint32_t& lo) {
  uint32_t a = (uint32_t)e, b = (uint32_t)(e >> 32);
  hi = (a >> 16) | (b & 0xFFFF0000u);
  lo = (a & 0xFFFFu) | (b << 16);
}

// plain cacheable u64 load (addresses are write-once -> no stale-line hazard)
#define ALD(p) (*(p))

// ---------------------------------------------------------------------------
// Pack W [1024][4096] into MFMA B-fragment order, split bf16 hi/lo (proven).
// ---------------------------------------------------------------------------
__global__ __launch_bounds__(256) void pack_w_k(const float* __restrict__ W,
                                                ushort* __restrict__ hi,
                                                ushort* __restrict__ lo) {
  const int i = blockIdx.x * 256 + threadIdx.x;  // 524288 = 256*32*64
  const int lane = i & 63, kc = (i >> 6) & 31, bid = i >> 11;
  const int c = lane & 15;
  const int col = (c >> 2) * H_ + (bid << 2) + (c & 3);
  const int k0 = (kc << 5) + ((lane >> 4) << 3);
  const size_t o = ((size_t)(bid * 32 + kc) * 64 + lane) * 8;
#pragma unroll
  for (int e = 0; e < 8; ++e) {
    float v = W[(size_t)(k0 + e) * FH + col];
    ushort h = f2bf_(v);
    hi[o + e] = h;
    lo[o + e] = f2bf_(v - bf2f_(h));
  }
}

// ---------------------------------------------------------------------------
// x: f32 -> bf16 hi/lo planes. Zeroes the 9 barrier counters in block 0.
// ---------------------------------------------------------------------------
__global__ __launch_bounds__(256) void split_f32_k(const float* __restrict__ src,
                                                   ushort* __restrict__ hi,
                                                   ushort* __restrict__ lo,
                                                   unsigned* bar) {
  if (bar != nullptr && blockIdx.x == 0 && threadIdx.x < 9)
    bar[threadIdx.x * 32] = 0u;
  const size_t i = (size_t)blockIdx.x * 256 + threadIdx.x;
  float4 v = reinterpret_cast<const float4*>(src)[i];
  ushort4 h, l;
  h.x = f2bf_(v.x); l.x = f2bf_(v.x - bf2f_(h.x));
  h.y = f2bf_(v.y); l.y = f2bf_(v.y - bf2f_(h.y));
  h.z = f2bf_(v.z); l.z = f2bf_(v.z - bf2f_(h.z));
  h.w = f2bf_(v.w); l.w = f2bf_(v.w - bf2f_(h.w));
  reinterpret_cast<ushort4*>(hi)[i] = h;
  reinterpret_cast<ushort4*>(lo)[i] = l;
}

// h0 f32 -> packed u32 (hi16:lo16). 64 blocks x 256 thr x 4 elems.
__global__ __launch_bounds__(256) void conv_h0pk_k(const float* __restrict__ src,
                                                   uint32_t* __restrict__ dst) {
  const int i = blockIdx.x * 256 + threadIdx.x;  // 16384 float4s
  float4 v = reinterpret_cast<const float4*>(src)[i];
  uint4 o;
  {
    ushort h = f2bf_(v.x); o.x = ((uint32_t)h << 16) | f2bf_(v.x - bf2f_(h));
  }
  {
    ushort h = f2bf_(v.y); o.y = ((uint32_t)h << 16) | f2bf_(v.y - bf2f_(h));
  }
  {
    ushort h = f2bf_(v.z); o.z = ((uint32_t)h << 16) | f2bf_(v.z - bf2f_(h));
  }
  {
    ushort h = f2bf_(v.w); o.w = ((uint32_t)h << 16) | f2bf_(v.w - bf2f_(h));
  }
  reinterpret_cast<uint4*>(dst)[i] = o;
}

// ---------------------------------------------------------------------------
// Persistent fused LSTM scan, round-9 skeleton + L2-cacheable h reads:
// - h state lives in a UNIQUE-ADDRESS ring hseq[0..T] (256 KB per step).
//   Writes: relaxed-agent atomic stores (write-through to MALL, proven r9).
//   Reads: plain cacheable loads of virgin addresses -> L2 demand-fill from
//   MALL, 32x reuse per XCD (r9's bypass reads caused 64 MB/step MALL traffic).
// - fence-free two-level barrier (proven r9), Wh in LDS, depth-2 prefetch.
// 256 blocks x 512 thr; block owns 4 h-cols. Waves: mt=w&3, kh=w>>2
// (0 -> h@Wh, 1 -> x_t@Wx). Split-bf16: D = Ah*Bh + Ah*Bl + Al*Bh.
// ---------------------------------------------------------------------------
__global__ __launch_bounds__(512, 2) void lstm_persist_mfma(
    const ushort* __restrict__ Whh_g, const ushort* __restrict__ Whl_g,
    const ushort* __restrict__ Wxh, const ushort* __restrict__ Wxl,
    const ushort* __restrict__ xh, const ushort* __restrict__ xl,
    const float* __restrict__ bias,
    uint32_t* __restrict__ hseq,
    float* __restrict__ out, unsigned* __restrict__ bar) {
  extern __shared__ char ldsraw[];
  bf16x8* const WhH = (bf16x8*)ldsraw;       // 2048 units (32 KB)
  bf16x8* const WhL = WhH + 2048;            // 2048 units (32 KB)
  float* const pre = (float*)(WhL + 2048);   // 128*17 floats (8704 B)

  const int tid = threadIdx.x, bid = blockIdx.x;
  const int lane = tid & 63, w = tid >> 6;
  const int mt = w & 3, kh = w >> 2;
  const int arow = (mt << 4) | (lane & 15);
  const int kg = lane >> 4;
  const int dc = lane & 15, dr = (lane >> 4) << 2;
  const int en = tid >> 2, ejj = tid & 3;

  float bias4[4] = {0.f, 0.f, 0.f, 0.f};
  float creg = 0.f;
  if (tid < 256) {
#pragma unroll
    for (int g = 0; g < 4; ++g) bias4[g] = bias[g * H_ + (bid << 2) + ejj];
  }

  // one-time Wh stage into LDS (identity copy of packed layout)
  {
    const bf16x8* gh = reinterpret_cast<const bf16x8*>(Whh_g) + (size_t)bid * 2048;
    const bf16x8* gl = reinterpret_cast<const bf16x8*>(Whl_g) + (size_t)bid * 2048;
#pragma unroll
    for (int r = 0; r < 4; ++r) {
      int u = tid + (r << 9);
      WhH[u] = gh[u];
      WhL[u] = gl[u];
    }
  }
  __syncthreads();

  // Wx global fragment bases (x-wave)
  const bf16x8* Bxh = reinterpret_cast<const bf16x8*>(Wxh) + (size_t)bid * 2048 + lane;
  const bf16x8* Bxl = reinterpret_cast<const bf16x8*>(Wxl) + (size_t)bid * 2048 + lane;

  unsigned* const leaf = bar + 32 + ((bid & 7) << 5);

  for (int t = 0; t < T_; ++t) {
    f32x4 acc0 = {0.f, 0.f, 0.f, 0.f};
    f32x4 acc1 = {0.f, 0.f, 0.f, 0.f};

    if (kh == 0) {
      // ---- h @ Wh : A via cacheable u64 loads of hseq[t], B from LDS ----
      const unsigned long long* Apk =
          (const unsigned long long*)(hseq + (size_t)t * 65536) +
          arow * 512 + kg * 4;

      unsigned long long pa0, pa1, pa2, pa3, pb0, pb1, pb2, pb3;
      unsigned long long pc0, pc1, pc2, pc3, pd0, pd1, pd2, pd3;
      unsigned long long qa0, qa1, qa2, qa3, qb0, qb1, qb2, qb3;
      unsigned long long qc0, qc1, qc2, qc3, qd0, qd1, qd2, qd3;

#define HLD(P, CH)                                                            \
  {                                                                           \
    const unsigned long long* ap_ = Apk + ((CH) << 6);                        \
    P##a0 = ALD(ap_ + 0);  P##a1 = ALD(ap_ + 1);                              \
    P##a2 = ALD(ap_ + 2);  P##a3 = ALD(ap_ + 3);                              \
    P##b0 = ALD(ap_ + 16); P##b1 = ALD(ap_ + 17);                             \
    P##b2 = ALD(ap_ + 18); P##b3 = ALD(ap_ + 19);                             \
    P##c0 = ALD(ap_ + 32); P##c1 = ALD(ap_ + 33);                             \
    P##c2 = ALD(ap_ + 34); P##c3 = ALD(ap_ + 35);                             \
    P##d0 = ALD(ap_ + 48); P##d1 = ALD(ap_ + 49);                             \
    P##d2 = ALD(ap_ + 50); P##d3 = ALD(ap_ + 51);                             \
  }

#define HKC(E0, E1, E2, E3, KCG, ACC)                                         \
  {                                                                           \
    union { uint32_t u[4]; bf16x8 v; } fh_, fl_;                              \
    unpk2_(E0, fh_.u[0], fl_.u[0]);                                           \
    unpk2_(E1, fh_.u[1], fl_.u[1]);                                           \
    unpk2_(E2, fh_.u[2], fl_.u[2]);                                           \
    unpk2_(E3, fh_.u[3], fl_.u[3]);                                           \
    bf16x8 bh_ = WhH[((KCG) << 6) + lane];                                    \
    bf16x8 bl_ = WhL[((KCG) << 6) + lane];                                    \
    ACC = __builtin_amdgcn_mfma_f32_16x16x32_bf16(fh_.v, bh_, ACC, 0, 0, 0);  \
    ACC = __builtin_amdgcn_mfma_f32_16x16x32_bf16(fh_.v, bl_, ACC, 0, 0, 0);  \
    ACC = __builtin_amdgcn_mfma_f32_16x16x32_bf16(fl_.v, bh_, ACC, 0, 0, 0);  \
  }

#define HCOMP(P, CH)                                                          \
  HKC(P##a0, P##a1, P##a2, P##a3, (CH) * 4 + 0, acc0)                         \
  HKC(P##b0, P##b1, P##b2, P##b3, (CH) * 4 + 1, acc1)                         \
  HKC(P##c0, P##c1, P##c2, P##c3, (CH) * 4 + 2, acc0)                         \
  HKC(P##d0, P##d1, P##d2, P##d3, (CH) * 4 + 3, acc1)

      HLD(p, 0)
      HLD(q, 1) HCOMP(p, 0)
      HLD(p, 2) HCOMP(q, 1)
      HLD(q, 3) HCOMP(p, 2)
      HLD(p, 4) HCOMP(q, 3)
      HLD(q, 5) HCOMP(p, 4)
      HLD(p, 6) HCOMP(q, 5)
      HLD(q, 7) HCOMP(p, 6)
      HCOMP(q, 7)
#undef HLD
#undef HKC
#undef HCOMP
    } else {
      // ---- x_t @ Wx : cacheable loads (round-8/9 structure, proven) ----
      const ushort* Ah = xh + ((size_t)arow * T_ + t) * D_ + (kg << 3);
      const ushort* Al = xl + ((size_t)arow * T_ + t) * D_ + (kg << 3);

      bf16x8 pAH0, pAH1, pAH2, pAH3, pAL0, pAL1, pAL2, pAL3;
      bf16x8 pBH0, pBH1, pBH2, pBH3, pBL0, pBL1, pBL2, pBL3;
      bf16x8 qAH0, qAH1, qAH2, qAH3, qAL0, qAL1, qAL2, qAL3;
      bf16x8 qBH0, qBH1, qBH2, qBH3, qBL0, qBL1, qBL2, qBL3;

#define XLD(P, CH)                                                            \
  {                                                                           \
    const int kb = (CH) << 2;                                                 \
    P##AH0 = *reinterpret_cast<const bf16x8*>(Ah + ((kb + 0) << 5));          \
    P##AH1 = *reinterpret_cast<const bf16x8*>(Ah + ((kb + 1) << 5));          \
    P##AH2 = *reinterpret_cast<const bf16x8*>(Ah + ((kb + 2) << 5));          \
    P##AH3 = *reinterpret_cast<const bf16x8*>(Ah + ((kb + 3) << 5));          \
    P##AL0 = *reinterpret_cast<const bf16x8*>(Al + ((kb + 0) << 5));          \
    P##AL1 = *reinterpret_cast<const bf16x8*>(Al + ((kb + 1) << 5));          \
    P##AL2 = *reinterpret_cast<const bf16x8*>(Al + ((kb + 2) << 5));          \
    P##AL3 = *reinterpret_cast<const bf16x8*>(Al + ((kb + 3) << 5));          \
    P##BH0 = Bxh[(kb + 0) << 6];                                              \
    P##BH1 = Bxh[(kb + 1) << 6];                                              \
    P##BH2 = Bxh[(kb + 2) << 6];                                              \
    P##BH3 = Bxh[(kb + 3) << 6];                                              \
    P##BL0 = Bxl[(kb + 0) << 6];                                              \
    P##BL1 = Bxl[(kb + 1) << 6];                                              \
    P##BL2 = Bxl[(kb + 2) << 6];                                              \
    P##BL3 = Bxl[(kb + 3) << 6];                                              \
  }

#define XCOMP(P)                                                              \
  {                                                                           \
    acc0 = __builtin_amdgcn_mfma_f32_16x16x32_bf16(P##AH0, P##BH0, acc0, 0, 0, 0); \
    acc1 = __builtin_amdgcn_mfma_f32_16x16x32_bf16(P##AH1, P##BH1, acc1, 0, 0, 0); \
    acc0 = __builtin_amdgcn_mfma_f32_16x16x32_bf16(P##AH0, P##BL0, acc0, 0, 0, 0); \
    acc1 = __builtin_amdgcn_mfma_f32_16x16x32_bf16(P##AH1, P##BL1, acc1, 0, 0, 0); \
    acc0 = __builtin_amdgcn_mfma_f32_16x16x32_bf16(P##AL0, P##BH0, acc0, 0, 0, 0); \
    acc1 = __builtin_amdgcn_mfma_f32_16x16x32_bf16(P##AL1, P##BH1, acc1, 0, 0, 0); \
    acc0 = __builtin_amdgcn_mfma_f32_16x16x32_bf16(P##AH2, P##BH2, acc0, 0, 0, 0); \
    acc1 = __builtin_amdgcn_mfma_f32_16x16x32_bf16(P##AH3, P##BH3, acc1, 0, 0, 0); \
    acc0 = __builtin_amdgcn_mfma_f32_16x16x32_bf16(P##AH2, P##BL2, acc0, 0, 0, 0); \
    acc1 = __builtin_amdgcn_mfma_f32_16x16x32_bf16(P##AH3, P##BL3, acc1, 0, 0, 0); \
    acc0 = __builtin_amdgcn_mfma_f32_16x16x32_bf16(P##AL2, P##BH2, acc0, 0, 0, 0); \
    acc1 = __builtin_amdgcn_mfma_f32_16x16x32_bf16(P##AL3, P##BH3, acc1, 0, 0, 0); \
  }

      XLD(p, 0)
      XLD(q, 1) XCOMP(p)
      XLD(p, 2) XCOMP(q)
      XLD(q, 3) XCOMP(p)
      XLD(p, 4) XCOMP(q)
      XLD(q, 5) XCOMP(p)
      XLD(p, 6) XCOMP(q)
      XLD(q, 7) XCOMP(p)
      XCOMP(q)
#undef XLD
#undef XCOMP
    }

    f32x4 accs = acc0 + acc1;

    // D layout (m89-verified): col = lane&15, row = (lane>>4)*4 + r
#pragma unroll
    for (int r = 0; r < 4; ++r)
      pre[((kh << 6) + (mt << 4) + dr + r) * 17 + dc] = accs[r];
    __syncthreads();

    if (tid < 256) {
      float a[4];
#pragma unroll
      for (int g = 0; g < 4; ++g)
        a[g] = pre[en * 17 + (g << 2) + ejj] +
               pre[(64 + en) * 17 + (g << 2) + ejj] + bias4[g];
      float iv = 1.f / (1.f + __expf(-a[0]));
      float fv = 1.f / (1.f + __expf(-a[1]));
      float ov = 1.f / (1.f + __expf(-a[2]));
      float gv = tanhf(a[3]);
      creg = fmaf(fv, creg, iv * gv);
      float hn = ov * tanhf(creg);
      out[(size_t)en * ((size_t)T_ * H_) + (size_t)t * H_ + (bid << 2) + ejj] = hn;
      ushort hh = f2bf_(hn);
      uint32_t pk = ((uint32_t)hh << 16) | f2bf_(hn - bf2f_(hh));
      __hip_atomic_store(&hseq[(size_t)(t + 1) * 65536 + en * H_ + (bid << 2) + ejj],
                         pk, __ATOMIC_RELAXED, __HIP_MEMORY_SCOPE_AGENT);
    }

    // ---- fence-free two-level grid barrier (all relaxed atomics) ----
    asm volatile("s_waitcnt vmcnt(0)" ::: "memory");
    __syncthreads();
    if (tid == 0) {
      unsigned old = __hip_atomic_fetch_add(leaf, 1u, __ATOMIC_RELAXED,
                                            __HIP_MEMORY_SCOPE_AGENT);
      if (old == 32u * (unsigned)(t + 1) - 1u)
        __hip_atomic_fetch_add(bar, 1u, __ATOMIC_RELAXED,
                               __HIP_MEMORY_SCOPE_AGENT);
      while (__hip_atomic_load(bar, __ATOMIC_RELAXED,
                               __HIP_MEMORY_SCOPE_AGENT) < 8u * (unsigned)(t + 1))
        __builtin_amdgcn_s_sleep(1);
    }
    __syncthreads();
  }
}

// ---------------------------------------------------------------------------
// Fallback (tiny ws): fused per-step VALU kernel (round-1 proven). Slow.
// ---------------------------------------------------------------------------
__global__ __launch_bounds__(256) void lstm_step_fb(
    const float* __restrict__ xt, const float* __restrict__ Wx,
    const float* __restrict__ Wh, const float* __restrict__ bias,
    const float* __restrict__ h_prev, long long hstride,
    float* __restrict__ cbuf, float* __restrict__ h_out, int first) {
  __shared__ float hS[32][128];
  __shared__ float wT[32][132];
  __shared__ float pre[32][34];
  const int tid = threadIdx.x;
  const int colblk = blockIdx.x & 127;
  const int nh = blockIdx.x >> 7;
  const int j0 = colblk << 3;
  const int n0 = nh << 5;
  const int ng = tid >> 4, cg2 = tid & 15;
  const int na = ng << 1, ca = cg2 << 1;

  float acc[2][2] = {{0.f, 0.f}, {0.f, 0.f}};

#pragma unroll
  for (int pr = 0; pr < 2; ++pr) {
    const float* src = (pr == 0) ? h_prev : xt;
    long long sstr = (pr == 0) ? hstride : (long long)T_ * D_;
    const float* W = (pr == 0) ? Wh : Wx;
    for (int k0 = 0; k0 < 1024; k0 += 128) {
      __syncthreads();
#pragma unroll
      for (int p = 0; p < 4; ++p) {
        int idx = tid + (p << 8);
        int r = idx >> 5, c4 = (idx & 31) << 2;
        *reinterpret_cast<float4*>(&hS[r][c4]) =
            *reinterpret_cast<const float4*>(src + (size_t)(n0 + r) * sstr + k0 + c4);
      }
#pragma unroll
      for (int p = 0; p < 4; ++p) {
        int idx = tid + (p << 8);
        int k = idx >> 3, sub = idx & 7;
        int g = sub >> 1, hf = (sub & 1) << 2;
        float4 v = *reinterpret_cast<const float4*>(
            W + (size_t)(k0 + k) * FH + g * H_ + j0 + hf);
        int cb = (g << 3) + hf;
        wT[cb][k] = v.x; wT[cb + 1][k] = v.y; wT[cb + 2][k] = v.z; wT[cb + 3][k] = v.w;
      }
      __syncthreads();
#pragma unroll
      for (int kk = 0; kk < 128; kk += 4) {
        float4 h0v = *reinterpret_cast<const float4*>(&hS[na][kk]);
        float4 h1v = *reinterpret_cast<const float4*>(&hS[na + 1][kk]);
        float4 w0 = *reinterpret_cast<const float4*>(&wT[ca][kk]);
        float4 w1 = *reinterpret_cast<const float4*>(&wT[ca + 1][kk]);
        acc[0][0] = fmaf(h0v.x, w0.x, acc[0][0]); acc[0][0] = fmaf(h0v.y, w0.y, acc[0][0]);
        acc[0][0] = fmaf(h0v.z, w0.z, acc[0][0]); acc[0][0] = fmaf(h0v.w, w0.w, acc[0][0]);
        acc[0][1] = fmaf(h0v.x, w1.x, acc[0][1]); acc[0][1] = fmaf(h0v.y, w1.y, acc[0][1]);
        acc[0][1] = fmaf(h0v.z, w1.z, acc[0][1]); acc[0][1] = fmaf(h0v.w, w1.w, acc[0][1]);
        acc[1][0] = fmaf(h1v.x, w0.x, acc[1][0]); acc[1][0] = fmaf(h1v.y, w0.y, acc[1][0]);
        acc[1][0] = fmaf(h1v.z, w0.z, acc[1][0]); acc[1][0] = fmaf(h1v.w, w0.w, acc[1][0]);
        acc[1][1] = fmaf(h1v.x, w1.x, acc[1][1]); acc[1][1] = fmaf(h1v.y, w1.y, acc[1][1]);
        acc[1][1] = fmaf(h1v.z, w1.z, acc[1][1]); acc[1][1] = fmaf(h1v.w, w1.w, acc[1][1]);
      }
    }
  }

  pre[na][ca] = acc[0][0];
  pre[na][ca + 1] = acc[0][1];
  pre[na + 1][ca] = acc[1][0];
  pre[na + 1][ca + 1] = acc[1][1];
  __syncthreads();

  const int nl = tid >> 3, jl = tid & 7;
  const int n = n0 + nl;
  const int jg = j0 + jl;
  float ai = pre[nl][jl] + bias[jg];
  float af = pre[nl][8 + jl] + bias[H_ + jg];
  float ao = pre[nl][16 + jl] + bias[2 * H_ + jg];
  float ag = pre[nl][24 + jl] + bias[3 * H_ + jg];
  float cp = first ? 0.0f : cbuf[n * H_ + jg];
  float iv = 1.f / (1.f + __expf(-ai));
  float fv = 1.f / (1.f + __expf(-af));
  float ov = 1.f / (1.f + __expf(-ao));
  float gv = tanhf(ag);
  float cn = fmaf(fv, cp, iv * gv);
  cbuf[n * H_ + jg] = cn;
  h_out[(size_t)n * ((size_t)T_ * H_) + jg] = ov * tanhf(cn);
}

// ---------------------------------------------------------------------------
extern "C" void kernel_launch(void* const* d_in, const int* in_sizes, int n_in,
                              void* d_out, int out_size, void* d_ws, size_t ws_size,
                              hipStream_t stream) {
  (void)in_sizes; (void)n_in; (void)out_size;
  const float* x  = (const float*)d_in[0];
  const float* h0 = (const float*)d_in[1];
  const float* Wx = (const float*)d_in[2];
  const float* Wh = (const float*)d_in[3];
  const float* b  = (const float*)d_in[4];
  float* out = (float*)d_out;

  const size_t MB = 1u << 20;
  char* p = (char*)d_ws;

  if (ws_size >= 300 * MB) {
    unsigned* bar = (unsigned*)p;
    ushort* Whh = (ushort*)(p + 1 * MB);
    ushort* Whl = (ushort*)(p + 9 * MB);
    ushort* Wxh = (ushort*)(p + 17 * MB);
    ushort* Wxl = (ushort*)(p + 25 * MB);
    uint32_t* hseq = (uint32_t*)(p + 33 * MB);  // 513 * 256 KB = 128.25 MB
    ushort* xh = (ushort*)(p + 168 * MB);       // 64 MB
    ushort* xl = (ushort*)(p + 232 * MB);       // 64 MB (ends at 296 MB)

    pack_w_k<<<dim3(2048), dim3(256), 0, stream>>>(Wh, Whh, Whl);
    pack_w_k<<<dim3(2048), dim3(256), 0, stream>>>(Wx, Wxh, Wxl);
    // x: 8,388,608 float4 -> 32768 blocks (zeroes bar counters)
    split_f32_k<<<dim3(32768), dim3(256), 0, stream>>>(x, xh, xl, bar);
    // h0 -> packed u32 into hseq[0]
    conv_h0pk_k<<<dim3(64), dim3(256), 0, stream>>>(h0, hseq);

    const unsigned SH = 2048 * 16 * 2 + 128 * 17 * 4;  // 74240 B
    hipFuncSetAttribute((const void*)lstm_persist_mfma,
                        hipFuncAttributeMaxDynamicSharedMemorySize, (int)SH);
    lstm_persist_mfma<<<dim3(256), dim3(512), SH, stream>>>(
        Whh, Whl, Wxh, Wxl, xh, xl, b, hseq, out, bar);
  } else {
    float* cbuf = (float*)p;  // 256 KB
    for (int t = 0; t < T_; ++t) {
      const float* hp = (t == 0) ? h0 : out + (size_t)(t - 1) * H_;
      long long hstr = (t == 0) ? (long long)H_ : (long long)T_ * H_;
      lstm_step_fb<<<dim3(256), dim3(256), 0, stream>>>(
          x + (size_t)t * D_, Wx, Wh, b, hp, hstr, cbuf,
          out + (size_t)t * H_, t == 0);
    }
  }
}